// Round 9
// baseline (146.488 us; speedup 1.0000x reference)
//
#include <hip/hip_runtime.h>
#include <math.h>

#define N_SETS 4096
#define ENC_BLOCKS 768
#define DEC_SPB 4
#define DEC_BLOCKS (N_SETS / DEC_SPB)   // 1024

typedef _Float16 f16;
typedef __attribute__((ext_vector_type(8))) _Float16 f16x8;
typedef __attribute__((ext_vector_type(4))) _Float16 f16x4;
typedef __attribute__((ext_vector_type(4))) float     f32x4;

template <int V> struct IC { static constexpr int value = V; };

// ---------------- ws layout ----------------
#define WS_PE    0         // fp32 [64][256]  65536
#define WS_QH    65536     // f16  [64][32]   4096
#define WS_WKV   69632     // f16  [64][256]  32768  (rows 0-31 Wk, 32-63 Wv)
#define WS_WMAPH 102400    // f16  [256][32]  16384
#define WS_PEH   118784    // f16  [64][256]  32768
#define WS_PTR   151552    // int  [4097]
#define WS_ZT    169984    // f16  [4096][32v][32k]  8 MB (ws is ~800 MB)

// aux1: blocks [0,768) -> batch_ptr + out2 echo; blocks [768,832) -> pe table
__global__ void k_aux1(const int* __restrict__ batch, float* __restrict__ out2,
                       int* __restrict__ ptr, int N, float* __restrict__ pe) {
    int blk = blockIdx.x;
    if (blk < 768) {
        int i = blk * 256 + threadIdx.x;
        if (i >= N) return;
        int b = batch[i];
        out2[i] = (float)b;
        if (i == 0 || batch[i - 1] != b) ptr[b] = i;
        if (i == N - 1) ptr[N_SETS] = N;
    } else {
        int idx = (blk - 768) * 256 + threadIdx.x;   // 0..16383
        int p = idx >> 8, i = idx & 255;
        float e   = (float)(2 * (i / 2)) / 256.0f;
        float inv = powf(10000.0f, -e);
        float ang = (float)p * inv;
        pe[idx] = (i & 1) ? cosf(ang) : sinf(ang);
    }
}

// aux2: [0,96) weight f16 convert; [96,160) peh convert; [160,168) qh
__global__ void k_aux2(const float* __restrict__ Wk, const float* __restrict__ Wv,
                       const float* __restrict__ Wq, const float* __restrict__ Wmap,
                       const float* __restrict__ pe, f16* __restrict__ wkv,
                       f16* __restrict__ wmaph, f16* __restrict__ peh,
                       f16* __restrict__ qh) {
    int blk = blockIdx.x;
    if (blk < 96) {
        int idx = blk * 256 + threadIdx.x;           // 0..24575
        if (idx < 16384) {
            int j = idx >> 8, d = idx & 255;
            float v = (j < 32) ? Wk[j * 256 + d] : Wv[(j - 32) * 256 + d];
            wkv[idx] = (f16)v;
        } else {
            int i2 = idx - 16384;
            wmaph[i2] = (f16)Wmap[i2];
        }
    } else if (blk < 160) {
        int idx = (blk - 96) * 256 + threadIdx.x;    // 0..16383
        peh[idx] = (f16)pe[idx];
    } else {
        int idx = (blk - 160) * 256 + threadIdx.x;   // 0..2047
        int pos = idx >> 5, k = idx & 31;
        const float* pr = pe + pos * 256;
        const float* wr = Wq + k * 256;
        float s = 0.f;
        for (int d = 0; d < 256; d += 4) {
            float4 a = *(const float4*)(pr + d);
            float4 b = *(const float4*)(wr + d);
            s += a.x * b.x + a.y * b.y + a.z * b.z + a.w * b.w;
        }
        qh[idx] = (f16)s;
    }
}

// ---------------- encoder: x -> zT (global) ----------------
// 768 blocks (3/CU, all resident), 4 waves, 5-6 sets/block, 1 barrier/set.
// LDS 49152 B: [0,32768) wsh f16 [64][256] swz ((j&7)<<4);
//              [32768,49152) ysh ping-pong 2 x (f16 [64c][64r] swz ((c&7)<<4))
__global__ __launch_bounds__(256, 3) void k_enc(
        const float* __restrict__ x,   const f16* __restrict__ wkv,
        const f16* __restrict__ peh,   const int* __restrict__ ptr,
        f16* __restrict__ zt) {
    __shared__ char lds[49152];

    const int t    = threadIdx.x;
    const int wv   = t >> 6;
    const int l15  = t & 15;
    const int lhi  = (t & 63) >> 4;
    const int arow = 16 * wv + l15;
    const int swz7 = (l15 & 7) << 4;

    const int g0  = (blockIdx.x * N_SETS) / ENC_BLOCKS;
    const int g1  = ((blockIdx.x + 1) * N_SETS) / ENC_BLOCKS;
    const int cnt = g1 - g0;

    // ---- stage wsh (Wk|Wv) ----
    #pragma unroll
    for (int i2 = 0; i2 < 8; ++i2) {
        int c = t + 256 * i2;
        int j = c >> 5, d0 = (c & 31) * 8;
        *(f16x8*)(lds + ((j * 512 + d0 * 2) ^ ((j & 7) << 4))) =
            *(const f16x8*)(wkv + j * 256 + d0);
    }
    // ---- per-lane PE fragment ----
    f16x8 pef[8];
    #pragma unroll
    for (int ks = 0; ks < 8; ++ks)
        pef[ks] = *(const f16x8*)(peh + arow * 256 + ks * 32 + lhi * 8);

    // ---- prefetch first set's x rows ----
    float4 xf[16];
    {
        const int s0 = ptr[g0], n0 = ptr[g0 + 1] - ptr[g0];
        if (arow < n0) {
            const float* xr = x + (size_t)(s0 + arow) * 256 + lhi * 8;
            #pragma unroll
            for (int ks = 0; ks < 8; ++ks) {
                xf[2 * ks]     = *(const float4*)(xr + ks * 32);
                xf[2 * ks + 1] = *(const float4*)(xr + ks * 32 + 4);
            }
        }
    }
    __syncthreads();

    // G2: Z(set g2) = YV^T*YK from ysh buffer yb -> global zT[g2]
    auto gemm2 = [&](int g2, int n2, char* yb) {
        const int nks = ((n2 + 31) & ~31) >> 5;
        const int it = wv >> 1, jt = wv & 1;
        f32x4 zacc = {0.f, 0.f, 0.f, 0.f};
        const int ca = 32 + 16 * it + l15, cb = 16 * jt + l15;
        for (int ks = 0; ks < nks; ++ks) {
            const int r2 = ks * 64 + lhi * 16;
            f16x8 av = *(const f16x8*)(yb + ((ca * 128 + r2) ^ swz7));
            f16x8 bk = *(const f16x8*)(yb + ((cb * 128 + r2) ^ swz7));
            zacc = __builtin_amdgcn_mfma_f32_16x16x32_f16(av, bk, zacc, 0, 0, 0);
        }
        f16x4 h4;
        #pragma unroll
        for (int q = 0; q < 4; ++q) h4[q] = (f16)zacc[q];
        const int zv = 16 * jt + l15, zk0 = 16 * it + lhi * 4;
        *(f16x4*)(zt + (size_t)g2 * 1024 + zv * 32 + zk0) = h4;
    };

    int gprev = 0, nprev = 0;
    for (int j = 0; j < cnt; ++j) {
        const int g = g0 + j;
        const int s = ptr[g], n = ptr[g + 1] - s;
        const int n32 = (n + 31) & ~31;
        char* ycur = lds + 32768 + (j & 1) * 8192;

        // build areg from prefetched xf (+PE), zero masked rows
        f16x8 areg[8];
        if (arow < n) {
            #pragma unroll
            for (int ks = 0; ks < 8; ++ks) {
                float4 a = xf[2 * ks], a2 = xf[2 * ks + 1];
                f16x8 h;
                h[0]=(f16)a.x;  h[1]=(f16)a.y;  h[2]=(f16)a.z;  h[3]=(f16)a.w;
                h[4]=(f16)a2.x; h[5]=(f16)a2.y; h[6]=(f16)a2.z; h[7]=(f16)a2.w;
                areg[ks] = h + pef[ks];
            }
        } else {
            #pragma unroll
            for (int ks = 0; ks < 8; ++ks) {
                f16x8 h;
                #pragma unroll
                for (int ii = 0; ii < 8; ++ii) h[ii] = (f16)0.f;
                areg[ks] = h;
            }
        }
        // prefetch next set's x (in flight across barrier)
        if (j + 1 < cnt) {
            const int s1 = ptr[g + 1], n1 = ptr[g + 2] - ptr[g + 1];
            if (arow < n1) {
                const float* xr1 = x + (size_t)(s1 + arow) * 256 + lhi * 8;
                #pragma unroll
                for (int ks = 0; ks < 8; ++ks) {
                    xf[2 * ks]     = *(const float4*)(xr1 + ks * 32);
                    xf[2 * ks + 1] = *(const float4*)(xr1 + ks * 32 + 4);
                }
            }
        }
        // finish previous set's Z while this set's G1 runs in the same interval
        if (j > 0) gemm2(gprev, nprev, lds + 32768 + ((j - 1) & 1) * 8192);

        // ---- GEMM1: Y = (X+PE)*Wkv^T -> ycur (transposed) ----
        if (16 * wv < n32) {
            f32x4 acc[4];
            #pragma unroll
            for (int nt = 0; nt < 4; ++nt) acc[nt] = (f32x4){0.f, 0.f, 0.f, 0.f};
            #pragma unroll
            for (int ks = 0; ks < 8; ++ks) {
                #pragma unroll
                for (int nt = 0; nt < 4; ++nt) {
                    f16x8 bf = *(const f16x8*)(lds +
                        (((16 * nt + l15) * 512 + ks * 64 + lhi * 16) ^ swz7));
                    acc[nt] = __builtin_amdgcn_mfma_f32_16x16x32_f16(areg[ks], bf, acc[nt], 0, 0, 0);
                }
            }
            const int row0 = 16 * wv + lhi * 4;
            #pragma unroll
            for (int nt = 0; nt < 4; ++nt) {
                const int col = 16 * nt + l15;
                f16x4 h4;
                #pragma unroll
                for (int q = 0; q < 4; ++q) h4[q] = (f16)acc[nt][q];
                *(f16x4*)(ycur + ((col * 128 + row0 * 2) ^ swz7)) = h4;
            }
        }
        __syncthreads();
        gprev = g; nprev = n;
    }
    gemm2(gprev, nprev, lds + 32768 + ((cnt - 1) & 1) * 8192);
}

// ---------------- decoder: zT -> out ----------------
// One wave per set, zero barriers. Q/Wmap/bmap/z all in registers; D
// transposed through a private 4 KB LDS slice (same-wave ordering).
__global__ __launch_bounds__(256, 3) void k_dec(
        const f16* __restrict__ zt,    const f16* __restrict__ wmaph,
        const f16* __restrict__ qh,    const float* __restrict__ bmap,
        const int* __restrict__ ptr,   float* __restrict__ out) {
    __shared__ char lds[16384];
    const int t    = threadIdx.x;
    const int wid  = t >> 6;
    const int l15  = t & 15;
    const int lhi  = (t & 63) >> 4;
    const int swz7 = (l15 & 7) << 4;
    char* dsh = lds + wid * 4096;     // private [64m][32v] f16 swz ((m&7)<<4)

    // per-lane constants
    f16x8 bw[16];
    float bm[16];
    #pragma unroll
    for (int nt = 0; nt < 16; ++nt) {
        bw[nt] = *(const f16x8*)(wmaph + (16 * nt + l15) * 32 + lhi * 8);
        bm[nt] = bmap[16 * nt + l15];
    }
    f16x8 qf[4];
    #pragma unroll
    for (int mt = 0; mt < 4; ++mt)
        qf[mt] = *(const f16x8*)(qh + (16 * mt + l15) * 32 + lhi * 8);

    const int g = blockIdx.x * DEC_SPB + wid;
    const int s = ptr[g], n = ptr[g + 1] - s;

    // z B-frags: zT[v][k], lane col v, k-span lhi*8..+8 (16B contiguous)
    const f16* ztg = zt + (size_t)g * 1024;
    const f16x8 bz0 = *(const f16x8*)(ztg + l15 * 32 + lhi * 8);
    const f16x8 bz1 = *(const f16x8*)(ztg + (16 + l15) * 32 + lhi * 8);

    float* ob = out + (size_t)s * 256;

    auto decode = [&](auto nmtc) {
        constexpr int NMT = decltype(nmtc)::value;
        // G3: D = Q * Z -> dsh
        #pragma unroll
        for (int mt = 0; mt < NMT; ++mt) {
            f32x4 d0 = {0.f, 0.f, 0.f, 0.f}, d1 = {0.f, 0.f, 0.f, 0.f};
            d0 = __builtin_amdgcn_mfma_f32_16x16x32_f16(qf[mt], bz0, d0, 0, 0, 0);
            d1 = __builtin_amdgcn_mfma_f32_16x16x32_f16(qf[mt], bz1, d1, 0, 0, 0);
            #pragma unroll
            for (int q = 0; q < 4; ++q) {
                const int m = 16 * mt + lhi * 4 + q;
                *(f16*)(dsh + ((m * 64 + l15 * 2) ^ ((m & 7) << 4)))        = (f16)d0[q];
                *(f16*)(dsh + ((m * 64 + (16 + l15) * 2) ^ ((m & 7) << 4))) = (f16)d1[q];
            }
        }
        // G4: out = D * Wmap^T + bmap
        #pragma unroll
        for (int mt = 0; mt < NMT; ++mt) {
            f16x8 ad = *(const f16x8*)(dsh + (((16 * mt + l15) * 64 + lhi * 16) ^ swz7));
            const int row0 = 16 * mt + lhi * 4;
            #pragma unroll
            for (int nt = 0; nt < 16; ++nt) {
                f32x4 o = {0.f, 0.f, 0.f, 0.f};
                o = __builtin_amdgcn_mfma_f32_16x16x32_f16(ad, bw[nt], o, 0, 0, 0);
                #pragma unroll
                for (int q = 0; q < 4; ++q)
                    ob[(size_t)(row0 + q) * 256 + 16 * nt + l15] = o[q] + bm[nt];
            }
        }
    };
    if (n > 32) decode(IC<4>{});
    else        decode(IC<2>{});
}

extern "C" void kernel_launch(void* const* d_in, const int* in_sizes, int n_in,
                              void* d_out, int out_size, void* d_ws, size_t ws_size,
                              hipStream_t stream) {
    const float* x    = (const float*)d_in[0];
    const int*   batch= (const int*)  d_in[1];
    const float* Wk   = (const float*)d_in[2];
    const float* Wv   = (const float*)d_in[3];
    const float* Wq   = (const float*)d_in[4];
    const float* Wmap = (const float*)d_in[5];
    const float* bmap = (const float*)d_in[6];
    float* out = (float*)d_out;

    const int N = in_sizes[1];                 // 196608 rows
    float* pe    = (float*)((char*)d_ws + WS_PE);
    f16*   qh    = (f16*)  ((char*)d_ws + WS_QH);
    f16*   wkv   = (f16*)  ((char*)d_ws + WS_WKV);
    f16*   wmaph = (f16*)  ((char*)d_ws + WS_WMAPH);
    f16*   peh   = (f16*)  ((char*)d_ws + WS_PEH);
    int*   ptr   = (int*)  ((char*)d_ws + WS_PTR);
    f16*   zt    = (f16*)  ((char*)d_ws + WS_ZT);
    float* out2  = out + (size_t)N * 256;      // output 1: batch echo as floats

    k_aux1<<<832, 256, 0, stream>>>(batch, out2, ptr, N, pe);
    k_aux2<<<168, 256, 0, stream>>>(Wk, Wv, Wq, Wmap, pe, wkv, wmaph, peh, qh);
    k_enc<<<ENC_BLOCKS, 256, 0, stream>>>(x, wkv, peh, ptr, zt);
    k_dec<<<DEC_BLOCKS, 256, 0, stream>>>(zt, wmaph, qh, bmap, ptr, out);
}

// Round 10
// 111.557 us; speedup vs baseline: 1.3131x; 1.3131x over previous
//
#include <hip/hip_runtime.h>
#include <math.h>

#define N_SETS 4096
#define SETS_PER_BLOCK 8
#define GRID_MAIN (N_SETS / SETS_PER_BLOCK)   // 512 blocks, all co-resident (2/CU)

typedef _Float16 f16;
typedef __attribute__((ext_vector_type(8))) _Float16 f16x8;
typedef __attribute__((ext_vector_type(4))) _Float16 f16x4;
typedef __attribute__((ext_vector_type(4))) float     f32x4;

// ---------------- ws layout ----------------
#define WS_PE    0         // fp32 [64][256]  65536
#define WS_QH    65536     // f16  [64][32]   4096
#define WS_WKV   69632     // f16  [64][256]  32768  (rows 0-31 Wk, 32-63 Wv)
#define WS_WMAPH 102400    // f16  [256][32]  16384
#define WS_PEH   118784    // f16  [64][256]  32768
#define WS_PTR   151552    // int  [4097]

// Non-draining barrier: LDS visibility (lgkmcnt) + s_barrier, but global
// loads/stores stay IN FLIGHT across it (unlike __syncthreads' vmcnt(0)).
__device__ __forceinline__ void lds_barrier() {
    asm volatile("s_waitcnt lgkmcnt(0)" ::: "memory");
    __builtin_amdgcn_s_barrier();
    __builtin_amdgcn_sched_barrier(0);
}

// aux1: blocks [0,768) -> batch_ptr + out2 echo; blocks [768,832) -> pe table
__global__ void k_aux1(const int* __restrict__ batch, float* __restrict__ out2,
                       int* __restrict__ ptr, int N, float* __restrict__ pe) {
    int blk = blockIdx.x;
    if (blk < 768) {
        int i = blk * 256 + threadIdx.x;
        if (i >= N) return;
        int b = batch[i];
        out2[i] = (float)b;
        if (i == 0 || batch[i - 1] != b) ptr[b] = i;
        if (i == N - 1) ptr[N_SETS] = N;
    } else {
        int idx = (blk - 768) * 256 + threadIdx.x;   // 0..16383
        int p = idx >> 8, i = idx & 255;
        float e   = (float)(2 * (i / 2)) / 256.0f;
        float inv = powf(10000.0f, -e);
        float ang = (float)p * inv;
        pe[idx] = (i & 1) ? cosf(ang) : sinf(ang);
    }
}

// aux2: [0,96) weight f16 convert; [96,160) peh convert; [160,168) qh
__global__ void k_aux2(const float* __restrict__ Wk, const float* __restrict__ Wv,
                       const float* __restrict__ Wq, const float* __restrict__ Wmap,
                       const float* __restrict__ pe, f16* __restrict__ wkv,
                       f16* __restrict__ wmaph, f16* __restrict__ peh,
                       f16* __restrict__ qh) {
    int blk = blockIdx.x;
    if (blk < 96) {
        int idx = blk * 256 + threadIdx.x;           // 0..24575
        if (idx < 16384) {
            int j = idx >> 8, d = idx & 255;
            float v = (j < 32) ? Wk[j * 256 + d] : Wv[(j - 32) * 256 + d];
            wkv[idx] = (f16)v;
        } else {
            int i2 = idx - 16384;
            wmaph[i2] = (f16)Wmap[i2];
        }
    } else if (blk < 160) {
        int idx = (blk - 96) * 256 + threadIdx.x;    // 0..16383
        peh[idx] = (f16)pe[idx];
    } else {
        int idx = (blk - 160) * 256 + threadIdx.x;   // 0..2047
        int pos = idx >> 5, k = idx & 31;
        const float* pr = pe + pos * 256;
        const float* wr = Wq + k * 256;
        float s = 0.f;
        for (int d = 0; d < 256; d += 4) {
            float4 a = *(const float4*)(pr + d);
            float4 b = *(const float4*)(wr + d);
            s += a.x * b.x + a.y * b.y + a.z * b.z + a.w * b.w;
        }
        qh[idx] = (f16)s;
    }
}

// Fused encoder+decoder, 8 sets/block, 4 waves. Non-draining barriers keep
// the cross-set x-prefetch and out-stores in flight across all sync points.
// LDS map (47104 B -> 2 blocks/CU, 512 blocks all resident):
//   [0,     32768)  wsh f16 [64][256] swz ((j&7)<<4)  (Wk 0-31, Wv 32-63)
//   [32768, 40960)  ysh f16 [64c][64r] swz ((c&7)<<4)
//   [40960, 43008)  zT  f16 [32c][32r] swz ((c&3)<<4)
//   [43008, 47104)  dsh f16 [64m][32v] swz ((m&7)<<4)
// Barriers/set: post-G1, post-G2, post-G3 (all lgkm-only). G4 overlaps the
// next set's G1 (disjoint LDS regions; proof in round-10 notes).
__global__ __launch_bounds__(256, 2) void k_main(
        const float* __restrict__ x,     const f16* __restrict__ wkv,
        const f16* __restrict__ wmaph,   const f16* __restrict__ qh,
        const f16* __restrict__ peh,     const float* __restrict__ bmap,
        const int* __restrict__ ptr,     float* __restrict__ out) {
    __shared__ char lds[47104];
    char* ysh = lds + 32768;
    char* zsh = lds + 40960;
    char* dsh = lds + 43008;

    const int t    = threadIdx.x;
    const int wv   = t >> 6;
    const int l15  = t & 15;
    const int lhi  = (t & 63) >> 4;       // 0..3
    const int arow = 16 * wv + l15;
    const int swz7 = (l15 & 7) << 4;

    int pv[SETS_PER_BLOCK + 1];
    #pragma unroll
    for (int i = 0; i <= SETS_PER_BLOCK; ++i)
        pv[i] = ptr[blockIdx.x * SETS_PER_BLOCK + i];

    // ---- stage wsh (Wk|Wv) ----
    #pragma unroll
    for (int i2 = 0; i2 < 8; ++i2) {
        int c = t + 256 * i2;
        int j = c >> 5, d0 = (c & 31) * 8;
        *(f16x8*)(lds + ((j * 512 + d0 * 2) ^ ((j & 7) << 4))) =
            *(const f16x8*)(wkv + j * 256 + d0);
    }
    // ---- per-lane set-invariant registers ----
    f16x8 pef[8];
    #pragma unroll
    for (int ks = 0; ks < 8; ++ks)
        pef[ks] = *(const f16x8*)(peh + arow * 256 + ks * 32 + lhi * 8);
    const f16x8 qreg = *(const f16x8*)(qh + arow * 32 + lhi * 8);
    // G4 (swapped): wave wv owns out cols 64wv..64wv+63; Wmap A-frags + bias C
    f16x8 bwreg[4];
    f32x4 biasc[4];
    #pragma unroll
    for (int i = 0; i < 4; ++i) {
        const int dcol = 64 * wv + 16 * i;
        bwreg[i] = *(const f16x8*)(wmaph + (dcol + l15) * 32 + lhi * 8);
        biasc[i] = *(const f32x4*)(bmap + dcol + lhi * 4);
    }

    // ---- prefetch set 0's x rows ----
    float4 xf[16];
    {
        const int s0 = pv[0], n0 = pv[1] - pv[0];
        if (arow < n0) {
            const float* xr = x + (size_t)(s0 + arow) * 256 + lhi * 8;
            #pragma unroll
            for (int ks = 0; ks < 8; ++ks) {
                xf[2 * ks]     = *(const float4*)(xr + ks * 32);
                xf[2 * ks + 1] = *(const float4*)(xr + ks * 32 + 4);
            }
        }
    }
    lds_barrier();

    for (int j = 0; j < SETS_PER_BLOCK; ++j) {
        const int s = pv[j], n = pv[j + 1] - s;
        const int n32 = (n + 31) & ~31;

        // convert current x + PE -> areg (f16)
        f16x8 areg[8];
        if (arow < n) {
            #pragma unroll
            for (int ks = 0; ks < 8; ++ks) {
                float4 a = xf[2 * ks], a2 = xf[2 * ks + 1];
                f16x8 h;
                h[0]=(f16)a.x;  h[1]=(f16)a.y;  h[2]=(f16)a.z;  h[3]=(f16)a.w;
                h[4]=(f16)a2.x; h[5]=(f16)a2.y; h[6]=(f16)a2.z; h[7]=(f16)a2.w;
                areg[ks] = h + pef[ks];
            }
        } else {
            #pragma unroll
            for (int ks = 0; ks < 8; ++ks) {
                f16x8 h;
                #pragma unroll
                for (int ii = 0; ii < 8; ++ii) h[ii] = (f16)0.f;
                areg[ks] = h;
            }
        }
        // prefetch next set's x: stays in flight across all barriers below
        if (j + 1 < SETS_PER_BLOCK) {
            const int s1 = pv[j + 1], n1 = pv[j + 2] - pv[j + 1];
            if (arow < n1) {
                const float* xr1 = x + (size_t)(s1 + arow) * 256 + lhi * 8;
                #pragma unroll
                for (int ks = 0; ks < 8; ++ks) {
                    xf[2 * ks]     = *(const float4*)(xr1 + ks * 32);
                    xf[2 * ks + 1] = *(const float4*)(xr1 + ks * 32 + 4);
                }
            }
        }

        // ---- GEMM1: Y = (X+PE)*Wkv^T -> yshT (transposed) ----
        if (16 * wv < n32) {
            f32x4 acc[4];
            #pragma unroll
            for (int nt = 0; nt < 4; ++nt) acc[nt] = (f32x4){0.f, 0.f, 0.f, 0.f};
            #pragma unroll
            for (int ks = 0; ks < 8; ++ks) {
                #pragma unroll
                for (int nt = 0; nt < 4; ++nt) {
                    f16x8 bf = *(const f16x8*)(lds +
                        (((16 * nt + l15) * 512 + ks * 64 + lhi * 16) ^ swz7));
                    acc[nt] = __builtin_amdgcn_mfma_f32_16x16x32_f16(areg[ks], bf, acc[nt], 0, 0, 0);
                }
            }
            const int row0 = 16 * wv + lhi * 4;
            #pragma unroll
            for (int nt = 0; nt < 4; ++nt) {
                const int col = 16 * nt + l15;
                f16x4 h4;
                #pragma unroll
                for (int q = 0; q < 4; ++q) h4[q] = (f16)acc[nt][q];
                *(f16x4*)(ysh + ((col * 128 + row0 * 2) ^ swz7)) = h4;
            }
        }
        lds_barrier();

        // ---- GEMM2: Z = YV^T * YK -> zT ----
        {
            const int it = wv >> 1, jt = wv & 1;
            f32x4 zacc = {0.f, 0.f, 0.f, 0.f};
            const int ca = 32 + 16 * it + l15, cb = 16 * jt + l15;
            const int nks = n32 >> 5;
            for (int ks = 0; ks < nks; ++ks) {
                const int r2 = ks * 64 + lhi * 16;
                f16x8 av = *(const f16x8*)(ysh + ((ca * 128 + r2) ^ swz7));
                f16x8 bk = *(const f16x8*)(ysh + ((cb * 128 + r2) ^ swz7));
                zacc = __builtin_amdgcn_mfma_f32_16x16x32_f16(av, bk, zacc, 0, 0, 0);
            }
            const int zc = 16 * jt + l15, zr0 = 16 * it + lhi * 4;
            f16x4 h4;
            #pragma unroll
            for (int q = 0; q < 4; ++q) h4[q] = (f16)zacc[q];
            *(f16x4*)(zsh + ((zc * 64 + zr0 * 2) ^ ((l15 & 3) << 4))) = h4;
        }
        lds_barrier();

        // ---- GEMM3: dec = query * Z -> dsh ----
        if (16 * wv < n) {
            const int k2 = lhi * 16;
            f16x8 bz0 = *(const f16x8*)(zsh + ((l15 * 64 + k2) ^ ((l15 & 3) << 4)));
            f16x8 bz1 = *(const f16x8*)(zsh + (((16 + l15) * 64 + k2) ^ ((l15 & 3) << 4)));
            f32x4 dd0 = {0.f, 0.f, 0.f, 0.f}, dd1 = {0.f, 0.f, 0.f, 0.f};
            dd0 = __builtin_amdgcn_mfma_f32_16x16x32_f16(qreg, bz0, dd0, 0, 0, 0);
            dd1 = __builtin_amdgcn_mfma_f32_16x16x32_f16(qreg, bz1, dd1, 0, 0, 0);
            #pragma unroll
            for (int q = 0; q < 4; ++q) {
                const int m = 16 * wv + lhi * 4 + q;
                *(f16*)(dsh + ((m * 64 + l15 * 2) ^ ((m & 7) << 4)))        = (f16)dd0[q];
                *(f16*)(dsh + ((m * 64 + (16 + l15) * 2) ^ ((m & 7) << 4))) = (f16)dd1[q];
            }
        }
        lds_barrier();

        // ---- GEMM4 (swapped, col-split): O^T tile = Wmap_frag x dec_frag ----
        // lane: out row m = 16mt + l15; cols 64wv+16i+lhi*4..+3 -> dwordx4 store
        {
            const int k2 = lhi * 16;
            float* ob = out + (size_t)s * 256;
            #pragma unroll
            for (int mt = 0; mt < 4; ++mt) {
                if (16 * mt < n) {
                    f16x8 ad = *(const f16x8*)(dsh + (((16 * mt + l15) * 64 + k2) ^ swz7));
                    #pragma unroll
                    for (int i = 0; i < 4; ++i) {
                        f32x4 o = __builtin_amdgcn_mfma_f32_16x16x32_f16(bwreg[i], ad, biasc[i], 0, 0, 0);
                        *(f32x4*)(ob + (size_t)(16 * mt + l15) * 256 + 64 * wv + 16 * i + lhi * 4) = o;
                    }
                }
            }
        }
        // no barrier: G4 reads dsh(j); next G1 writes ysh only. dsh(j+1) is
        // written in G3(j+1), which is two lds_barriers later -> safe.
    }
}

extern "C" void kernel_launch(void* const* d_in, const int* in_sizes, int n_in,
                              void* d_out, int out_size, void* d_ws, size_t ws_size,
                              hipStream_t stream) {
    const float* x    = (const float*)d_in[0];
    const int*   batch= (const int*)  d_in[1];
    const float* Wk   = (const float*)d_in[2];
    const float* Wv   = (const float*)d_in[3];
    const float* Wq   = (const float*)d_in[4];
    const float* Wmap = (const float*)d_in[5];
    const float* bmap = (const float*)d_in[6];
    float* out = (float*)d_out;

    const int N = in_sizes[1];                 // 196608 rows
    float* pe    = (float*)((char*)d_ws + WS_PE);
    f16*   qh    = (f16*)  ((char*)d_ws + WS_QH);
    f16*   wkv   = (f16*)  ((char*)d_ws + WS_WKV);
    f16*   wmaph = (f16*)  ((char*)d_ws + WS_WMAPH);
    f16*   peh   = (f16*)  ((char*)d_ws + WS_PEH);
    int*   ptr   = (int*)  ((char*)d_ws + WS_PTR);
    float* out2  = out + (size_t)N * 256;      // output 1: batch echo as floats

    k_aux1<<<832, 256, 0, stream>>>(batch, out2, ptr, N, pe);
    k_aux2<<<168, 256, 0, stream>>>(Wk, Wv, Wq, Wmap, pe, wkv, wmaph, peh, qh);
    k_main<<<GRID_MAIN, 256, 0, stream>>>(x, wkv, wmaph, qh, peh, bmap, ptr, out);
}